// Round 9
// baseline (129.555 us; speedup 1.0000x reference)
//
#include <hip/hip_runtime.h>
#include <hip/hip_bf16.h>

// Problem constants
#define BATCH  16384
#define GATES  1023
#define NPAD   1024
#define OUTF   128

typedef unsigned short ushortT;
typedef short bf16x8 __attribute__((ext_vector_type(8)));
typedef float f32x4 __attribute__((ext_vector_type(4)));
typedef float f32x16 __attribute__((ext_vector_type(16)));

__device__ inline float bf2f(ushortT u) {
    union { unsigned int i; float f; } v;
    v.i = ((unsigned int)u) << 16;
    return v.f;
}
__device__ inline ushortT f2bf(float f) {
    union { float f; unsigned int i; } v;
    v.f = f;
    unsigned int x = v.i;
    unsigned int r = (x + 0x7FFFu + ((x >> 16) & 1u)) >> 16;  // RNE
    return (ushortT)r;
}
__device__ inline unsigned pkbf(float lo, float hi) {
    __hip_bfloat162 h = __float22bfloat162_rn(float2{lo, hi});
    union { __hip_bfloat162 h; unsigned u; } c;
    c.h = h;
    return c.u;
}
// Row-XOR on ushort-index bits 3..5 (gate/leaf region). [R3-measured: 262K]
__device__ inline int swz8(int row) { return (((row ^ (row >> 3)) & 7) << 3); }

// async global->LDS, 16B/lane; lds base wave-uniform, HW writes base + lane*16.
__device__ inline void gl2lds16(const void* gptr, void* ldsptr) {
    __builtin_amdgcn_global_load_lds(
        (const __attribute__((address_space(1))) void*)gptr,
        (__attribute__((address_space(3))) void*)ldsptr, 16, 0, 0);
}

#define WAITV(N) asm volatile("s_waitcnt vmcnt(" #N ")" ::: "memory")
#define WAITL0() asm volatile("s_waitcnt lgkmcnt(0)" ::: "memory")
#define CFENCE() asm volatile("" ::: "memory")
#define HWBAR()  __builtin_amdgcn_s_barrier()

struct RunTag  { static constexpr bool last = false; };
struct LastTag { static constexpr bool last = true;  };

// ---------------- prep: gwT (tiled transpose+pad), zh, gbp ----------------
__global__ __launch_bounds__(256) void k_prep(const float* __restrict__ gw,
                                              const float* __restrict__ gb,
                                              const float* __restrict__ z,
                                              ushortT* __restrict__ gwT,
                                              float* __restrict__ gbp,
                                              ushortT* __restrict__ zh) {
    const int b = blockIdx.x, t = threadIdx.x;
    if (b < 64) {
        __shared__ ushortT tile[64][65];
        const int k0 = (b >> 4) * 64, n0 = (b & 15) * 64;
        const int tr = t >> 6, tc = t & 63;
#pragma unroll
        for (int p = 0; p < 16; ++p) {
            int k = p * 4 + tr;
            int n = n0 + tc;
            float v = (n < GATES) ? gw[(size_t)(k0 + k) * GATES + n] : 0.f;
            tile[k][tc] = f2bf(v);
        }
        __syncthreads();
#pragma unroll
        for (int p = 0; p < 2; ++p) {
            int nn = (t >> 3) + p * 32;
            int ks = (t & 7) * 8;
            ushortT o[8];
#pragma unroll
            for (int u = 0; u < 8; ++u) o[u] = tile[ks + u][nn];
            *(bf16x8*)(gwT + (size_t)(n0 + nn) * 256 + k0 + ks) = *(bf16x8*)o;
        }
    } else if (b < 128) {
        int i = (b - 64) * 256 + t;
        const float4* p = (const float4*)z + (size_t)i * 2;
        float4 a = p[0], c = p[1];
        union { unsigned u[4]; bf16x8 v; } o;
        o.u[0] = pkbf(a.x, a.y); o.u[1] = pkbf(a.z, a.w);
        o.u[2] = pkbf(c.x, c.y); o.u[3] = pkbf(c.z, c.w);
        *(bf16x8*)(zh + (size_t)i * 8) = o.v;
    } else {
#pragma unroll
        for (int u = 0; u < 4; ++u) {
            int id = t * 4 + u;
            gbp[id] = (id < GATES) ? gb[id] : 0.f;
        }
    }
}

// ---------------- mega: 64 rows/block, 1024 threads, AUTONOMOUS waves -------
// No lockstep phases. 5 barriers total. Per-wave private depth-2 register
// rings for B (1 load -> 1 MFMA(32x32x16) per step, WAITV(1) floor). x staged
// coalesced into sG[0..64KB) (pre-swizzled source), read to af[16] registers,
// then gates overwrite. P3 splits K across wave pairs (even/odd leaf blocks),
// 32KB LDS reduction. LDS 160KB, 1 block/CU, 4 waves/SIMD, VGPR<=128.
__global__ __launch_bounds__(1024, 4) void k_mega(const float* __restrict__ x,
                                                  const ushortT* __restrict__ gwT,
                                                  const float* __restrict__ gbp,
                                                  const ushortT* __restrict__ zh,
                                                  float* __restrict__ out) {
    __shared__ __align__(16) ushortT sG[64 * 1024];  // 128 KB (x-stage aliased)
    __shared__ __align__(16) float   sR[8192];       // 32 KB reduction

    const int tid = threadIdx.x;
    const int wave = tid >> 6, lane = tid & 63;
    const int h = lane >> 5, l31 = lane & 31;
    const int bm = blockIdx.x * 64;
    // P1 decomposition: 2M x 8N (wave tile 32 rows x 32 cols x K=256)
    const int wm1 = wave >> 3, wn1 = wave & 7;
    // P3 decomposition: 2K x 2M x 4N (wave tile 32 rows x 32 outf x K=512)
    const int kk = wave >> 3, wm3 = (wave >> 2) & 1, wn3 = wave & 3;

    // ---- prologue vmem: x-stage (4 rows/wave, swizzled src), bias, B-ring ---
    CFENCE();
#pragma unroll
    for (int i = 0; i < 4; ++i) {
        int r = wave * 4 + i;
        int rs = (r ^ (r >> 3)) & 7;
        gl2lds16(x + (size_t)(bm + r) * 256 + ((lane ^ rs) << 2),
                 (char*)sG + (size_t)r * 1024);
    }
    CFENCE();
    float bsA[4];
#pragma unroll
    for (int st = 0; st < 4; ++st) bsA[st] = gbp[wn1 * 128 + st * 32 + l31];
    // B-frag 32x32x16: lane holds col=l31, k=(h*8..+8); 16B identity loads.
    const ushortT* gwB = gwT + (size_t)(wn1 * 128 + l31) * 256 + h * 8;
    bf16x8 bq0 = *(const bf16x8*)(gwB);        // t=0: strip0 ks0
    bf16x8 bq1 = *(const bf16x8*)(gwB + 16);   // t=1: strip0 ks1
    WAITV(2);   // x + bias done; bq0/bq1 in flight
    HWBAR();    // all waves' x rows staged

    // ---- af[16]: A-frags from x-staged LDS (row=l31+wm1*32, k=c*16+h*8) ----
    bf16x8 af[16];
    {
        const int rL = wm1 * 32 + l31;
        const int rswzL = (rL ^ (rL >> 3)) & 7;
        const float* xrow = (const float*)((const char*)sG + (size_t)rL * 1024);
#pragma unroll
        for (int ks = 0; ks < 16; ++ks) {
            int s0 = ks * 4 + h * 2;
            f32x4 A0 = *(const f32x4*)(xrow + ((s0 ^ rswzL) << 2));
            f32x4 A1 = *(const f32x4*)(xrow + (((s0 + 1) ^ rswzL) << 2));
            union { unsigned u[4]; bf16x8 v; } o;
            o.u[0] = pkbf(A0[0], A0[1]); o.u[1] = pkbf(A0[2], A0[3]);
            o.u[2] = pkbf(A1[0], A1[1]); o.u[3] = pkbf(A1[2], A1[3]);
            af[ks] = o.v;
        }
    }
    WAITL0();
    HWBAR();    // all af reads done before gate-writes clobber x-region

    // ---- P1: 4 col-strips x 16 K-steps; barrier-free private pipeline ------
    auto p1_strip = [&](int strip, auto tag) {
        constexpr bool L = decltype(tag)::last;
        f32x16 acc = {};
#pragma unroll
        for (int ks = 0; ks < 16; ++ks) {
            if (L && ks == 15) { WAITV(0); } else { WAITV(1); }
            acc = __builtin_amdgcn_mfma_f32_32x32x16_bf16(
                af[ks], (ks & 1) ? bq1 : bq0, acc, 0, 0, 0);
            if (!L || ks < 14) {
                int t2 = strip * 16 + ks + 2;
                const bf16x8* src =
                    (const bf16x8*)(gwB + (t2 >> 4) * 8192 + (t2 & 15) * 16);
                if (ks & 1) bq1 = *src; else bq0 = *src;
            }
        }
        // epilogue: sigmoid -> sG gate slot ((col+1)&1023)^swz8(row)
        // C/D 32x32: col=l31, row = r + 8q + 4h  [guide m74/m101]
        const int col = wn1 * 128 + strip * 32 + l31;
        const int sl = (col + 1) & 1023;
        const float bs = bsA[strip];
#pragma unroll
        for (int q = 0; q < 4; ++q)
#pragma unroll
            for (int r = 0; r < 4; ++r) {
                int row = wm1 * 32 + 4 * h + 8 * q + r;
                float g = 1.f / (1.f + __expf(-(acc[q * 4 + r] + bs)));
                sG[(row << 10) + (sl ^ swz8(row))] = f2bf(g);
            }
    };
    p1_strip(0, RunTag{});
    p1_strip(1, RunTag{});
    p1_strip(2, RunTag{});
    p1_strip(3, LastTag{});

    // ---- P3 B-ring prologue issued EARLY (T14): rides under all of P2 ------
    const ushortT* zB = zh + (size_t)(wn3 * 32 + l31) * 1024 + kk * 8 + h * 16;
    bf16x8 zq0 = *(const bf16x8*)(zB);
    bf16x8 zq1 = *(const bf16x8*)(zB + 32);
    CFENCE();

    WAITL0(); HWBAR();   // all gates visible

    // ---- P2: tree; 4 rows per wave; conflict-free vector reads -------------
    {
        const int r0 = wave * 4;
        for (int rr = 0; rr < 4; ++rr) {
            const int row = r0 + rr;
            const int rowb = row << 10;
            const int x8 = swz8(row);
            float P = 1.f;
#pragma unroll
            for (int d = 0; d < 6; ++d) {
                int slot = (1 << d) + (lane >> (6 - d));
                float g = bf2f(sG[rowb + (slot ^ x8)]);
                int bit = (lane >> (5 - d)) & 1;
                P *= bit ? (1.f - g) : g;
            }
            float g6 = bf2f(sG[rowb + ((64 + lane) ^ x8)]);
            float va = P * g6, vb = P - va;
            unsigned w7 = *(const unsigned*)(sG + rowb + ((128 + 2 * lane) ^ x8));
            float v4[4];
            {
                float ga = bf2f((ushortT)w7), gbv = bf2f((ushortT)(w7 >> 16));
                v4[0] = va * ga;  v4[1] = va - v4[0];
                v4[2] = vb * gbv; v4[3] = vb - v4[2];
            }
            const unsigned* p8 = (const unsigned*)(sG + rowb + ((256 + 4 * lane) ^ x8));
            unsigned w8a = p8[0], w8b = p8[1];
            float v8[8];
            {
                float h0 = bf2f((ushortT)w8a), h1 = bf2f((ushortT)(w8a >> 16));
                float h2 = bf2f((ushortT)w8b), h3 = bf2f((ushortT)(w8b >> 16));
                v8[0] = v4[0] * h0; v8[1] = v4[0] - v8[0];
                v8[2] = v4[1] * h1; v8[3] = v4[1] - v8[2];
                v8[4] = v4[2] * h2; v8[5] = v4[2] - v8[4];
                v8[6] = v4[3] * h3; v8[7] = v4[3] - v8[6];
            }
            bf16x8 g9 = *(const bf16x8*)(sG + rowb + ((512 + 8 * lane) ^ x8));
            float v16[16];
#pragma unroll
            for (int t = 0; t < 8; ++t) {
                float g = bf2f((ushortT)g9[t]);
                float a = v8[t] * g;
                v16[2 * t] = a;
                v16[2 * t + 1] = v8[t] - a;
            }
            union { unsigned u[4]; bf16x8 v; } q0, q1;
#pragma unroll
            for (int t = 0; t < 4; ++t) q0.u[t] = pkbf(v16[2 * t], v16[2 * t + 1]);
#pragma unroll
            for (int t = 0; t < 4; ++t) q1.u[t] = pkbf(v16[8 + 2 * t], v16[9 + 2 * t]);
            int a0u = rowb + ((lane << 3) ^ x8);
            *(bf16x8*)(sG + a0u) = q0.v;
            *(bf16x8*)(sG + a0u + 512) = q1.v;
        }
    }
    WAITL0(); HWBAR();   // leaves visible

    // ---- P3: out = leaf @ z^T; K-split (kk: even/odd leaf blocks) ----------
    // step s covers leaf blocks 4s+2h+kk; A slot us=(kk<<9)+(((2s+h)<<3)^x8).
    f32x16 acc3 = {};
    {
        const int row3 = wm3 * 32 + l31;
        const int x83 = swz8(row3);
        const ushortT* aB = sG + ((size_t)row3 << 10) + (kk << 9);
#pragma unroll 2
        for (int s = 0; s < 30; ++s) {
            WAITV(1);
            int us = ((s << 4) + (h << 3)) ^ x83;
            bf16x8 a = *(const bf16x8*)(aB + us);
            acc3 = __builtin_amdgcn_mfma_f32_32x32x16_bf16(
                a, (s & 1) ? zq1 : zq0, acc3, 0, 0, 0);
            const bf16x8* src = (const bf16x8*)(zB + 32 * (s + 2));
            if (s & 1) zq1 = *src; else zq0 = *src;
        }
        WAITV(1);
        {
            int us = ((30 << 4) + (h << 3)) ^ x83;
            bf16x8 a = *(const bf16x8*)(aB + us);
            acc3 = __builtin_amdgcn_mfma_f32_32x32x16_bf16(a, zq0, acc3, 0, 0, 0);
        }
        WAITV(0);
        {
            int us = ((31 << 4) + (h << 3)) ^ x83;
            bf16x8 a = *(const bf16x8*)(aB + us);
            acc3 = __builtin_amdgcn_mfma_f32_32x32x16_bf16(a, zq1, acc3, 0, 0, 0);
        }
    }

    // ---- K-split reduction through sR (16 slices x 2KB, lane*16 layout) ----
    WAITL0();
    if (kk == 1) {
        float* d0 = sR + (size_t)(wave - 8) * 512 + lane * 4;
        float* d1 = sR + (size_t)wave * 512 + lane * 4;
        f32x4 t;
#pragma unroll
        for (int j = 0; j < 4; ++j) t[j] = acc3[j];
        *(f32x4*)(d0) = t;
#pragma unroll
        for (int j = 0; j < 4; ++j) t[j] = acc3[4 + j];
        *(f32x4*)(d0 + 256) = t;
#pragma unroll
        for (int j = 0; j < 4; ++j) t[j] = acc3[8 + j];
        *(f32x4*)(d1) = t;
#pragma unroll
        for (int j = 0; j < 4; ++j) t[j] = acc3[12 + j];
        *(f32x4*)(d1 + 256) = t;
        WAITL0();
    }
    HWBAR();
    if (kk == 0) {
        const float* s0 = sR + (size_t)wave * 512 + lane * 4;
        const float* s1 = sR + (size_t)(wave + 8) * 512 + lane * 4;
        f32x4 q0 = *(const f32x4*)(s0);
        f32x4 q1 = *(const f32x4*)(s0 + 256);
        f32x4 q2 = *(const f32x4*)(s1);
        f32x4 q3 = *(const f32x4*)(s1 + 256);
#pragma unroll
        for (int j = 0; j < 4; ++j) {
            acc3[j]      += q0[j];
            acc3[4 + j]  += q1[j];
            acc3[8 + j]  += q2[j];
            acc3[12 + j] += q3[j];
        }
        const int gm = bm + wm3 * 32 + 4 * h;
        const int gn = wn3 * 32 + l31;
#pragma unroll
        for (int q = 0; q < 4; ++q)
#pragma unroll
            for (int r = 0; r < 4; ++r)
                out[(size_t)(gm + 8 * q + r) * OUTF + gn] = acc3[q * 4 + r];
    }
}

// ---------------- launch ----------------
extern "C" void kernel_launch(void* const* d_in, const int* in_sizes, int n_in,
                              void* d_out, int out_size, void* d_ws, size_t ws_size,
                              hipStream_t stream) {
    const float* x  = (const float*)d_in[0];   // 16384 x 256
    const float* gw = (const float*)d_in[1];   // 256 x 1023
    const float* gb = (const float*)d_in[2];   // 1023
    const float* z  = (const float*)d_in[3];   // 128 x 1024
    float* out = (float*)d_out;                // 16384 x 128

    char* ws = (char*)d_ws;
    ushortT* gwT = (ushortT*)(ws + 0);       // 524,288 B
    ushortT* zh  = (ushortT*)(ws + 524288);  // 262,144 B
    float*   gbp = (float*)  (ws + 786432);  //   4,096 B (total < 1 MB)

    k_prep<<<129, 256, 0, stream>>>(gw, gb, z, gwT, gbp, zh);
    k_mega<<<256, 1024, 0, stream>>>(x, gwT, gbp, zh, out);
}